// Round 3
// baseline (865.324 us; speedup 1.0000x reference)
//
#include <hip/hip_runtime.h>
#include <hip/hip_bf16.h>
#include <stdint.h>

#define NT 4096   // tokens
#define DD 1024   // model dim
#define HH 4096   // hidden dim
#define NEXP 8    // experts
// TOP_K = 2

typedef __attribute__((ext_vector_type(8))) short bf16x8;
typedef __attribute__((ext_vector_type(4))) float f32x4;

// async global->LDS, 16B per lane; LDS dest is wave-uniform base + lane*16
#define GLOAD16(g, l) __builtin_amdgcn_global_load_lds( \
    (const __attribute__((address_space(1))) void*)(g), \
    (__attribute__((address_space(3))) void*)(l), 16, 0, 0)

__device__ inline ushort f2b(float f) {
  union { float f; uint32_t u; } v; v.f = f;
  uint32_t u = v.u;
  return (ushort)((u + 0x7fffu + ((u >> 16) & 1u)) >> 16);  // RNE
}

// ---- gating: softmax(x@Wg+bg); top-2 -> dense wgt, tidx/tval, counts -------
__global__ __launch_bounds__(256) void gating_kernel(
    const float* __restrict__ x, const float* __restrict__ Wg,
    const float* __restrict__ bg, float* __restrict__ wgt,
    int* __restrict__ tidx, float* __restrict__ tval, int* __restrict__ counts) {
  int gw = (blockIdx.x * 256 + threadIdx.x) >> 6;  // one wave per token
  int lane = threadIdx.x & 63;
  if (gw >= NT) return;
  const float* xr = x + (size_t)gw * DD;
  float acc[NEXP];
#pragma unroll
  for (int e = 0; e < NEXP; e++) acc[e] = 0.f;
  for (int d = lane; d < DD; d += 64) {
    float xv = xr[d];
    const float* wr = Wg + (size_t)d * NEXP;
#pragma unroll
    for (int e = 0; e < NEXP; e++) acc[e] += xv * wr[e];
  }
#pragma unroll
  for (int off = 32; off > 0; off >>= 1) {
#pragma unroll
    for (int e = 0; e < NEXP; e++) acc[e] += __shfl_xor(acc[e], off, 64);
  }
  float l[NEXP], m = -1e30f;
#pragma unroll
  for (int e = 0; e < NEXP; e++) { l[e] = acc[e] + bg[e]; m = fmaxf(m, l[e]); }
  float s = 0.f;
#pragma unroll
  for (int e = 0; e < NEXP; e++) { l[e] = expf(l[e] - m); s += l[e]; }
  float inv = 1.f / s;
  float v1 = -1.f, v2 = -1.f; int i1 = -1, i2 = -1;
#pragma unroll
  for (int e = 0; e < NEXP; e++) {
    float p = l[e] * inv;
    if (p > v1) { v2 = v1; i2 = i1; v1 = p; i1 = e; }
    else if (p > v2) { v2 = p; i2 = e; }
  }
  if (lane < NEXP) {
    float w = (lane == i1) ? v1 : ((lane == i2) ? v2 : 0.f);
    wgt[(size_t)gw * NEXP + lane] = w;
  }
  if (lane == 0) {
    tidx[gw * 2 + 0] = i1; tval[gw * 2 + 0] = v1;
    tidx[gw * 2 + 1] = i2; tval[gw * 2 + 1] = v2;
    atomicAdd(&counts[i1], 1);
    atomicAdd(&counts[i2], 1);
  }
}

// ---- base[e] = 128-aligned prefix of counts --------------------------------
__global__ void scan_kernel(const int* __restrict__ counts, int* __restrict__ base) {
  int b = 0;
#pragma unroll
  for (int e = 0; e < NEXP; e++) { base[e] = b; b += ((counts[e] + 127) >> 7) << 7; }
}

// ---- scatter tokens into expert-grouped pair list --------------------------
__global__ __launch_bounds__(256) void scatter_kernel(
    const int* __restrict__ tidx, const float* __restrict__ tval,
    const int* __restrict__ base, int* __restrict__ cursor,
    int* __restrict__ perm, float* __restrict__ pairw) {
  int t = blockIdx.x * 256 + threadIdx.x;
  if (t >= NT) return;
#pragma unroll
  for (int k = 0; k < 2; k++) {
    int e = tidx[t * 2 + k];
    int pos = atomicAdd(&cursor[e], 1);
    int p = base[e] + pos;
    perm[p] = t;
    pairw[p] = tval[t * 2 + k];
  }
}

// ---- fp32 -> bf16 elementwise (x) ------------------------------------------
__global__ __launch_bounds__(256) void cvt_x_kernel(
    const float* __restrict__ in, ushort* __restrict__ out, int n) {
  int i = (blockIdx.x * 256 + threadIdx.x) * 4;
  if (i >= n) return;
  float4 v = *(const float4*)(in + i);
  ushort4 o; o.x = f2b(v.x); o.y = f2b(v.y); o.z = f2b(v.z); o.w = f2b(v.w);
  *(ushort4*)(out + i) = o;
}

// ---- fp32 [R][C] -> bf16 [C][R], 64x64 tiles, swizzled bf16 LDS ------------
// Load: float4 coalesced; LDS: ushort T[64][68], col ^= ((r>>3)&7)<<3 swizzle
// (2-way max bank aliasing on both phases = free). Store: 16B vectorized.
__global__ __launch_bounds__(256) void transpose_cvt64_kernel(
    const float* __restrict__ in, ushort* __restrict__ out, int R, int C) {
  __shared__ __align__(16) ushort T[64 * 68];
  size_t eo = (size_t)blockIdx.z * (size_t)R * C;
  in += eo; out += eo;
  int r0 = blockIdx.y * 64, c0 = blockIdx.x * 64;
  int t = threadIdx.x;
  int lr = t >> 4;            // 0..15
  int lc = (t & 15) * 4;      // 0..60
#pragma unroll
  for (int i = 0; i < 4; i++) {
    int r = lr + i * 16;
    float4 v = *(const float4*)(in + (size_t)(r0 + r) * C + c0 + lc);
    ushort4 o; o.x = f2b(v.x); o.y = f2b(v.y); o.z = f2b(v.z); o.w = f2b(v.w);
    int cs = lc ^ (((r >> 3) & 7) << 3);   // swizzled col (lc%4 preserved)
    *(ushort4*)&T[r * 68 + cs] = o;
  }
  __syncthreads();
#pragma unroll
  for (int it = 0; it < 2; it++) {
    int task = it * 256 + t;
    int c = task >> 3;          // 0..63 output row (C-dim)
    int rr0 = (task & 7) * 8;   // 8 consecutive r
    uint w[4];
#pragma unroll
    for (int j = 0; j < 4; j++) {
      int ra = rr0 + 2 * j, rb = ra + 1;
      uint a = T[ra * 68 + (c ^ (((ra >> 3) & 7) << 3))];
      uint b = T[rb * 68 + (c ^ (((rb >> 3) & 7) << 3))];
      w[j] = a | (b << 16);
    }
    *(uint4*)(out + (size_t)(c0 + c) * R + r0 + rr0) = make_uint4(w[0], w[1], w[2], w[3]);
  }
}

// ---- GEMM: C[M][N] = A[M][K] @ Bt[N][K]^T, global_load_lds staging ---------
// MODE 1: store bf16(relu(acc+bias)) to Cout rows (pair/token index)
// MODE 2: accumulate w*(acc+bias) into out[token] (atomic when SPARSE)
// SPLITS: split-K factor (blockIdx.z = e*SPLITS + split); bias added by split 0
template <int MODE, bool SPARSE, int SPLITS>
__global__ __launch_bounds__(256) void gemm_bt_kernel(
    const ushort* __restrict__ A, const ushort* __restrict__ BtAll,
    const float* __restrict__ biasAll, void* __restrict__ Cout,
    const int* __restrict__ perm, const float* __restrict__ pairw,
    const float* __restrict__ wgtDense,
    const int* __restrict__ base, const int* __restrict__ cnt,
    int Nn, int K, int eFixed) {
  const int BK = 32;
  __shared__ __align__(16) ushort As[128 * BK];
  __shared__ __align__(16) ushort Bs[128 * BK];
  int e, sp, m0;
  if (SPARSE) {
    e = blockIdx.z / SPLITS;
    sp = blockIdx.z % SPLITS;
    if ((int)blockIdx.y * 128 >= cnt[e]) return;   // expert has no rows here
    m0 = base[e] + blockIdx.y * 128;
  } else {
    e = eFixed; sp = 0;
    m0 = blockIdx.y * 128;
  }
  int n0 = blockIdx.x * 128;
  const ushort* Bt = SPARSE ? BtAll + (size_t)e * Nn * K : BtAll;
  const float* bias = biasAll + (size_t)e * Nn;

  int tid = threadIdx.x, wv = tid >> 6, lane = tid & 63;
  // staging: wave wv stages rows [wv*32, wv*32+32); lane -> row lane>>2, 16B col
  int sr = lane >> 2;
  int sc = (lane & 3) * 8;  // ushort col
  int ar0 = m0 + wv * 32 + sr, ar1 = ar0 + 16;
  int64_t gr0, gr1;
  if (SPARSE && MODE == 1) { gr0 = perm[ar0]; gr1 = perm[ar1]; }
  else { gr0 = ar0; gr1 = ar1; }
  const ushort* gA0 = A + gr0 * (int64_t)K + sc;
  const ushort* gA1 = A + gr1 * (int64_t)K + sc;
  const ushort* gB0 = Bt + (int64_t)(n0 + wv * 32 + sr) * K + sc;
  const ushort* gB1 = gB0 + (int64_t)16 * K;
  ushort* lA0 = &As[(wv * 32) * BK];
  ushort* lA1 = &As[(wv * 32 + 16) * BK];
  ushort* lB0 = &Bs[(wv * 32) * BK];
  ushort* lB1 = &Bs[(wv * 32 + 16) * BK];

  int wr = (wv >> 1) * 64;   // wave's 64x64 quadrant
  int wc = (wv & 1) * 64;
  int lr = lane & 15;
  int kq = (lane >> 4) * 8;

  f32x4 acc[4][4];
#pragma unroll
  for (int i = 0; i < 4; i++)
#pragma unroll
    for (int j = 0; j < 4; j++) acc[i][j] = (f32x4)(0.f);

  int kb = (K / SPLITS) * sp, ke = kb + K / SPLITS;
  for (int k0 = kb; k0 < ke; k0 += BK) {
    __syncthreads();               // prior frag reads done before DMA lands
    GLOAD16(gA0 + k0, lA0);
    GLOAD16(gA1 + k0, lA1);
    GLOAD16(gB0 + k0, lB0);
    GLOAD16(gB1 + k0, lB1);
    __syncthreads();               // drains vmcnt -> tiles visible
    bf16x8 af[4], bfr[4];
#pragma unroll
    for (int i = 0; i < 4; i++)
      af[i] = *(const bf16x8*)&As[(wr + i * 16 + lr) * BK + kq];
#pragma unroll
    for (int j = 0; j < 4; j++)
      bfr[j] = *(const bf16x8*)&Bs[(wc + j * 16 + lr) * BK + kq];
#pragma unroll
    for (int i = 0; i < 4; i++)
#pragma unroll
      for (int j = 0; j < 4; j++)
        acc[i][j] = __builtin_amdgcn_mfma_f32_16x16x32_bf16(af[i], bfr[j],
                                                            acc[i][j], 0, 0, 0);
  }

  // epilogue: C/D layout col = lane&15, row = (lane>>4)*4 + reg
  int rq = (lane >> 4) * 4;
  if (MODE == 1) {
    ushort* Cb = (ushort*)Cout;
#pragma unroll
    for (int i = 0; i < 4; i++) {
#pragma unroll
      for (int r = 0; r < 4; r++) {
        int row = m0 + wr + i * 16 + rq + r;
#pragma unroll
        for (int j = 0; j < 4; j++) {
          int col = n0 + wc + j * 16 + lr;
          float v = acc[i][j][r] + bias[col];
          Cb[(size_t)row * Nn + col] = f2b(fmaxf(v, 0.f));
        }
      }
    }
  } else {
    float* Co = (float*)Cout;
#pragma unroll
    for (int i = 0; i < 4; i++) {
#pragma unroll
      for (int r = 0; r < 4; r++) {
        int row = m0 + wr + i * 16 + rq + r;
        if (SPARSE) {
          float w = pairw[row];
          if (w != 0.f) {
            int t = perm[row];
#pragma unroll
            for (int j = 0; j < 4; j++) {
              int col = n0 + wc + j * 16 + lr;
              float bterm = (sp == 0) ? bias[col] : 0.f;
              atomicAdd(&Co[(size_t)t * DD + col], w * (acc[i][j][r] + bterm));
            }
          }
        } else {
          float w = wgtDense[(size_t)row * NEXP + e];
          if (w != 0.f) {
#pragma unroll
            for (int j = 0; j < 4; j++) {
              int col = n0 + wc + j * 16 + lr;
              Co[(size_t)row * Nn + col] += w * (acc[i][j][r] + bias[col]);
            }
          }
        }
      }
    }
  }
}

extern "C" void kernel_launch(void* const* d_in, const int* in_sizes, int n_in,
                              void* d_out, int out_size, void* d_ws,
                              size_t ws_size, hipStream_t stream) {
  const float* x  = (const float*)d_in[0];
  const float* Wg = (const float*)d_in[1];
  const float* bg = (const float*)d_in[2];
  const float* W1 = (const float*)d_in[3];
  const float* b1 = (const float*)d_in[4];
  const float* W2 = (const float*)d_in[5];
  const float* b2 = (const float*)d_in[6];
  float* out = (float*)d_out;
  char* ws = (char*)d_ws;

  hipMemsetAsync(d_out, 0, (size_t)out_size * sizeof(float), stream);

  // ---- Tier A: sparse pair-grouped path. Needs ~218.4 MB workspace. ----
  const size_t XB_SZ   = (size_t)NT * DD * 2;          //   8 MiB
  const size_t WT_SZ   = (size_t)NEXP * DD * HH * 2;   //  64 MiB each
  const size_t HB_ROWS = 9216;                         // 8192 pairs + pad
  const size_t HB_SZ   = HB_ROWS * HH * 2;             //  72 MiB
  const size_t W1T_OFF = XB_SZ;
  const size_t W2T_OFF = W1T_OFF + WT_SZ;
  const size_t HB_OFF  = W2T_OFF + WT_SZ;
  const size_t SM_OFF  = HB_OFF + HB_SZ;
  const size_t TIER_A_NEED = SM_OFF + 275456;

  if (ws_size >= TIER_A_NEED) {
    ushort* xb   = (ushort*)ws;
    ushort* w1t  = (ushort*)(ws + W1T_OFF);
    ushort* w2t  = (ushort*)(ws + W2T_OFF);
    ushort* hbuf = (ushort*)(ws + HB_OFF);
    char* sm = ws + SM_OFF;
    int*   counts = (int*)(sm + 0);
    int*   cursor = (int*)(sm + 128);
    int*   base   = (int*)(sm + 256);
    int*   tidx   = (int*)(sm + 1024);
    float* tval   = (float*)(sm + 1024 + 32768);
    int*   perm   = (int*)(sm + 68608);
    float* pairw  = (float*)(sm + 105472);
    float* wgt    = (float*)(sm + 143360);  // dense table (sparse path: gating only)

    hipMemsetAsync(sm, 0, 142336, stream);  // counts/cursor/base/perm/pairw

    gating_kernel<<<NT / 4, 256, 0, stream>>>(x, Wg, bg, wgt, tidx, tval, counts);
    cvt_x_kernel<<<(NT * DD / 4 + 255) / 256, 256, 0, stream>>>(x, xb, NT * DD);
    scan_kernel<<<1, 1, 0, stream>>>(counts, base);
    scatter_kernel<<<NT / 256, 256, 0, stream>>>(tidx, tval, base, cursor, perm, pairw);

    // all-expert weight transposes (fp32 -> bf16, [R][C] -> [C][R])
    transpose_cvt64_kernel<<<dim3(HH / 64, DD / 64, NEXP), 256, 0, stream>>>(W1, w1t, DD, HH);
    transpose_cvt64_kernel<<<dim3(DD / 64, HH / 64, NEXP), 256, 0, stream>>>(W2, w2t, HH, DD);

    // h[p] = relu(x[perm[p]] @ W1_e + b1_e)   (merged over experts)
    gemm_bt_kernel<1, true, 1><<<dim3(HH / 128, NT / 128, NEXP), 256, 0, stream>>>(
        xb, w1t, b1, hbuf, perm, pairw, nullptr, base, counts, HH, DD, 0);
    // out[perm[p]] += pairw[p] * (h[p] @ W2_e + b2_e)   split-K=4
    gemm_bt_kernel<2, true, 4><<<dim3(DD / 128, NT / 128, NEXP * 4), 256, 0, stream>>>(
        hbuf, w2t, b2, out, perm, pairw, nullptr, base, counts, DD, HH, 0);
    return;
  }

  // ---- Tier B: dense per-expert path (round-1 footprint) ----
  ushort* xb  = (ushort*)ws;                         // 8 MiB
  ushort* hb  = (ushort*)(ws + (8u << 20));          // 32 MiB
  ushort* w1t = (ushort*)(ws + (42u << 20));         // 8 MiB
  ushort* w2t = (ushort*)(ws + (51u << 20));         // 8 MiB
  char* sm2 = ws + (59u << 20);
  int*   tidx   = (int*)(sm2);
  float* tval   = (float*)(sm2 + 32768);
  int*   counts = (int*)(sm2 + 65536);
  float* wgt    = (float*)(ws + (60u << 20));        // 128 KiB

  gating_kernel<<<NT / 4, 256, 0, stream>>>(x, Wg, bg, wgt, tidx, tval, counts);
  cvt_x_kernel<<<(NT * DD / 4 + 255) / 256, 256, 0, stream>>>(x, xb, NT * DD);

  for (int e = 0; e < NEXP; e++) {
    transpose_cvt64_kernel<<<dim3(HH / 64, DD / 64, 1), 256, 0, stream>>>(
        W1 + (size_t)e * DD * HH, w1t, DD, HH);
    gemm_bt_kernel<1, false, 1><<<dim3(HH / 128, NT / 128, 1), 256, 0, stream>>>(
        xb, w1t, b1, hb, nullptr, nullptr, nullptr, nullptr, nullptr, HH, DD, e);
    transpose_cvt64_kernel<<<dim3(DD / 64, HH / 64, 1), 256, 0, stream>>>(
        W2 + (size_t)e * HH * DD, w2t, HH, DD);
    gemm_bt_kernel<2, false, 1><<<dim3(DD / 128, NT / 128, 1), 256, 0, stream>>>(
        hb, w2t, b2, out, nullptr, nullptr, wgt, nullptr, nullptr, DD, HH, e);
  }
}

// Round 4
// 738.160 us; speedup vs baseline: 1.1723x; 1.1723x over previous
//
#include <hip/hip_runtime.h>
#include <hip/hip_bf16.h>
#include <stdint.h>

#define NT 4096   // tokens
#define DD 1024   // model dim
#define HH 4096   // hidden dim
#define NEXP 8    // experts
// TOP_K = 2

typedef __attribute__((ext_vector_type(8))) short bf16x8;
typedef __attribute__((ext_vector_type(4))) float f32x4;

// async global->LDS, 16B per lane; LDS dest is wave-uniform base + lane*16
#define GLOAD16(g, l) __builtin_amdgcn_global_load_lds( \
    (const __attribute__((address_space(1))) void*)(g), \
    (__attribute__((address_space(3))) void*)(l), 16, 0, 0)

__device__ inline ushort f2b(float f) {
  union { float f; uint32_t u; } v; v.f = f;
  uint32_t u = v.u;
  return (ushort)((u + 0x7fffu + ((u >> 16) & 1u)) >> 16);  // RNE
}

// ---- gating: softmax(x@Wg+bg); top-2 -> dense wgt, tidx/tval, counts -------
__global__ __launch_bounds__(256) void gating_kernel(
    const float* __restrict__ x, const float* __restrict__ Wg,
    const float* __restrict__ bg, float* __restrict__ wgt,
    int* __restrict__ tidx, float* __restrict__ tval, int* __restrict__ counts) {
  int gw = (blockIdx.x * 256 + threadIdx.x) >> 6;  // one wave per token
  int lane = threadIdx.x & 63;
  if (gw >= NT) return;
  const float* xr = x + (size_t)gw * DD;
  float acc[NEXP];
#pragma unroll
  for (int e = 0; e < NEXP; e++) acc[e] = 0.f;
  for (int d = lane; d < DD; d += 64) {
    float xv = xr[d];
    const float* wr = Wg + (size_t)d * NEXP;
#pragma unroll
    for (int e = 0; e < NEXP; e++) acc[e] += xv * wr[e];
  }
#pragma unroll
  for (int off = 32; off > 0; off >>= 1) {
#pragma unroll
    for (int e = 0; e < NEXP; e++) acc[e] += __shfl_xor(acc[e], off, 64);
  }
  float l[NEXP], m = -1e30f;
#pragma unroll
  for (int e = 0; e < NEXP; e++) { l[e] = acc[e] + bg[e]; m = fmaxf(m, l[e]); }
  float s = 0.f;
#pragma unroll
  for (int e = 0; e < NEXP; e++) { l[e] = expf(l[e] - m); s += l[e]; }
  float inv = 1.f / s;
  float v1 = -1.f, v2 = -1.f; int i1 = -1, i2 = -1;
#pragma unroll
  for (int e = 0; e < NEXP; e++) {
    float p = l[e] * inv;
    if (p > v1) { v2 = v1; i2 = i1; v1 = p; i1 = e; }
    else if (p > v2) { v2 = p; i2 = e; }
  }
  if (lane < NEXP) {
    float w = (lane == i1) ? v1 : ((lane == i2) ? v2 : 0.f);
    wgt[(size_t)gw * NEXP + lane] = w;
  }
  if (lane == 0) {
    tidx[gw * 2 + 0] = i1; tval[gw * 2 + 0] = v1;
    tidx[gw * 2 + 1] = i2; tval[gw * 2 + 1] = v2;
    atomicAdd(&counts[i1], 1);
    atomicAdd(&counts[i2], 1);
  }
}

// ---- base[e] = 128-aligned prefix of counts --------------------------------
__global__ void scan_kernel(const int* __restrict__ counts, int* __restrict__ base) {
  int b = 0;
#pragma unroll
  for (int e = 0; e < NEXP; e++) { base[e] = b; b += ((counts[e] + 127) >> 7) << 7; }
}

// ---- scatter tokens into expert-grouped pair list + inverse map ------------
__global__ __launch_bounds__(256) void scatter_kernel(
    const int* __restrict__ tidx, const float* __restrict__ tval,
    const int* __restrict__ base, int* __restrict__ cursor,
    int* __restrict__ perm, float* __restrict__ pairw,
    int* __restrict__ pos0, int* __restrict__ pos1) {
  int t = blockIdx.x * 256 + threadIdx.x;
  if (t >= NT) return;
#pragma unroll
  for (int k = 0; k < 2; k++) {
    int e = tidx[t * 2 + k];
    int pos = atomicAdd(&cursor[e], 1);
    int p = base[e] + pos;
    perm[p] = t;
    pairw[p] = tval[t * 2 + k];
    if (k == 0) pos0[t] = p; else pos1[t] = p;
  }
}

// ---- fp32 -> bf16 elementwise (x) ------------------------------------------
__global__ __launch_bounds__(256) void cvt_x_kernel(
    const float* __restrict__ in, ushort* __restrict__ out, int n) {
  int i = (blockIdx.x * 256 + threadIdx.x) * 4;
  if (i >= n) return;
  float4 v = *(const float4*)(in + i);
  ushort4 o; o.x = f2b(v.x); o.y = f2b(v.y); o.z = f2b(v.z); o.w = f2b(v.w);
  *(ushort4*)(out + i) = o;
}

// ---- fp32 [R][C] -> bf16 [C][R], 64x64 tiles, swizzled bf16 LDS ------------
__global__ __launch_bounds__(256) void transpose_cvt64_kernel(
    const float* __restrict__ in, ushort* __restrict__ out, int R, int C) {
  __shared__ __align__(16) ushort T[64 * 68];
  size_t eo = (size_t)blockIdx.z * (size_t)R * C;
  in += eo; out += eo;
  int r0 = blockIdx.y * 64, c0 = blockIdx.x * 64;
  int t = threadIdx.x;
  int lr = t >> 4;            // 0..15
  int lc = (t & 15) * 4;      // 0..60
#pragma unroll
  for (int i = 0; i < 4; i++) {
    int r = lr + i * 16;
    float4 v = *(const float4*)(in + (size_t)(r0 + r) * C + c0 + lc);
    ushort4 o; o.x = f2b(v.x); o.y = f2b(v.y); o.z = f2b(v.z); o.w = f2b(v.w);
    int cs = lc ^ (((r >> 3) & 7) << 3);   // swizzled col (lc%4 preserved)
    *(ushort4*)&T[r * 68 + cs] = o;
  }
  __syncthreads();
#pragma unroll
  for (int it = 0; it < 2; it++) {
    int task = it * 256 + t;
    int c = task >> 3;          // 0..63 output row (C-dim)
    int rr0 = (task & 7) * 8;   // 8 consecutive r
    uint w[4];
#pragma unroll
    for (int j = 0; j < 4; j++) {
      int ra = rr0 + 2 * j, rb = ra + 1;
      uint a = T[ra * 68 + (c ^ (((ra >> 3) & 7) << 3))];
      uint b = T[rb * 68 + (c ^ (((rb >> 3) & 7) << 3))];
      w[j] = a | (b << 16);
    }
    *(uint4*)(out + (size_t)(c0 + c) * R + r0 + rr0) = make_uint4(w[0], w[1], w[2], w[3]);
  }
}

// ---- GEMM: C[M][N] = A[M][K] @ Bt[N][K]^T ----------------------------------
// Double-buffered global_load_lds (1 barrier/iter), XOR-swizzled LDS chunks.
// MODE 1: store bf16(relu(acc+bias)) to Cout rows (pair index via perm gather)
// MODE 2 SPARSE: ybuf[row] = pairw[row]*(acc+bias)   (plain stores, no atomics)
// MODE 2 dense : out[row] += wgt[row][e]*(acc+bias)
template <int MODE, bool SPARSE>
__global__ __launch_bounds__(256) void gemm_bt_kernel(
    const ushort* __restrict__ A, const ushort* __restrict__ BtAll,
    const float* __restrict__ biasAll, void* __restrict__ Cout,
    const int* __restrict__ perm, const float* __restrict__ pairw,
    const float* __restrict__ wgtDense,
    const int* __restrict__ base, const int* __restrict__ cnt,
    int Nn, int K, int eFixed) {
  const int BK = 32;
  __shared__ __align__(16) ushort As[2][128 * BK];
  __shared__ __align__(16) ushort Bs[2][128 * BK];
  int e, m0;
  if (SPARSE) {
    e = blockIdx.z;
    if ((int)blockIdx.y * 128 >= cnt[e]) return;   // expert has no rows here
    m0 = base[e] + blockIdx.y * 128;
  } else {
    e = eFixed;
    m0 = blockIdx.y * 128;
  }
  int n0 = blockIdx.x * 128;
  const ushort* Bt = SPARSE ? BtAll + (size_t)e * Nn * K : BtAll;
  const float* bias = biasAll + (size_t)e * Nn;

  int tid = threadIdx.x, wv = tid >> 6, lane = tid & 63;
  // staging: wave wv stages rows [wv*32, wv*32+32); lane -> row sr, 16B chunk.
  // Source chunk XOR-swizzled by (row>>1)&3 so LDS phase conflicts are <=2-way.
  int sr = lane >> 2;
  int csw = ((lane & 3) ^ ((sr >> 1) & 3)) * 8;   // swizzled ushort offset
  int ar0 = m0 + wv * 32 + sr, ar1 = ar0 + 16;
  int64_t gr0, gr1;
  if (SPARSE && MODE == 1) { gr0 = perm[ar0]; gr1 = perm[ar1]; }
  else { gr0 = ar0; gr1 = ar1; }
  const ushort* gA0 = A + gr0 * (int64_t)K + csw;
  const ushort* gA1 = A + gr1 * (int64_t)K + csw;
  const ushort* gB0 = Bt + (int64_t)(n0 + wv * 32 + sr) * K + csw;
  const ushort* gB1 = gB0 + (int64_t)16 * K;
  int lds0 = (wv * 32) * BK;          // wave's ushort offset in As/Bs
  int lds1 = lds0 + 16 * BK;

  int wr = (wv >> 1) * 64;   // wave's 64x64 quadrant
  int wc = (wv & 1) * 64;
  int lr = lane & 15;
  int kq = (lane >> 4) * 8;
  int kqp = kq ^ (((lr >> 1) & 3) << 3);   // physical chunk (reader swizzle)

  f32x4 acc[4][4];
#pragma unroll
  for (int i = 0; i < 4; i++)
#pragma unroll
    for (int j = 0; j < 4; j++) acc[i][j] = (f32x4)(0.f);

  // prologue: tile 0 -> buf 0
  GLOAD16(gA0, &As[0][lds0]);
  GLOAD16(gA1, &As[0][lds1]);
  GLOAD16(gB0, &Bs[0][lds0]);
  GLOAD16(gB1, &Bs[0][lds1]);

  const int nIter = K / BK;
  int buf = 0;
  for (int it = 0; it < nIter; ++it) {
    __syncthreads();   // drains buf's DMA (in flight during prev compute)
    if (it + 1 < nIter) {
      int ko = (it + 1) * BK;
      GLOAD16(gA0 + ko, &As[buf ^ 1][lds0]);
      GLOAD16(gA1 + ko, &As[buf ^ 1][lds1]);
      GLOAD16(gB0 + ko, &Bs[buf ^ 1][lds0]);
      GLOAD16(gB1 + ko, &Bs[buf ^ 1][lds1]);
    }
    bf16x8 af[4], bfr[4];
#pragma unroll
    for (int i = 0; i < 4; i++)
      af[i] = *(const bf16x8*)&As[buf][(wr + i * 16 + lr) * BK + kqp];
#pragma unroll
    for (int j = 0; j < 4; j++)
      bfr[j] = *(const bf16x8*)&Bs[buf][(wc + j * 16 + lr) * BK + kqp];
#pragma unroll
    for (int i = 0; i < 4; i++)
#pragma unroll
      for (int j = 0; j < 4; j++)
        acc[i][j] = __builtin_amdgcn_mfma_f32_16x16x32_bf16(af[i], bfr[j],
                                                            acc[i][j], 0, 0, 0);
    buf ^= 1;
  }

  // epilogue: C/D layout col = lane&15, row = (lane>>4)*4 + reg
  int rq = (lane >> 4) * 4;
  if (MODE == 1) {
    ushort* Cb = (ushort*)Cout;
#pragma unroll
    for (int i = 0; i < 4; i++) {
#pragma unroll
      for (int r = 0; r < 4; r++) {
        int row = m0 + wr + i * 16 + rq + r;
#pragma unroll
        for (int j = 0; j < 4; j++) {
          int col = n0 + wc + j * 16 + lr;
          float v = acc[i][j][r] + bias[col];
          Cb[(size_t)row * Nn + col] = f2b(fmaxf(v, 0.f));
        }
      }
    }
  } else {
    float* Co = (float*)Cout;
#pragma unroll
    for (int i = 0; i < 4; i++) {
#pragma unroll
      for (int r = 0; r < 4; r++) {
        int row = m0 + wr + i * 16 + rq + r;
        if (SPARSE) {
          float w = pairw[row];   // 0 for pad rows -> writes 0, never combined
#pragma unroll
          for (int j = 0; j < 4; j++) {
            int col = n0 + wc + j * 16 + lr;
            Co[(size_t)row * Nn + col] = w * (acc[i][j][r] + bias[col]);
          }
        } else {
          float w = wgtDense[(size_t)row * NEXP + e];
          if (w != 0.f) {
#pragma unroll
            for (int j = 0; j < 4; j++) {
              int col = n0 + wc + j * 16 + lr;
              Co[(size_t)row * Nn + col] += w * (acc[i][j][r] + bias[col]);
            }
          }
        }
      }
    }
  }
}

// ---- combine: out[t] = ybuf[pos0[t]] + ybuf[pos1[t]] -----------------------
__global__ __launch_bounds__(256) void combine_kernel(
    const float* __restrict__ ybuf, const int* __restrict__ pos0,
    const int* __restrict__ pos1, float* __restrict__ out) {
  int t = blockIdx.x;
  int d = threadIdx.x * 4;
  const float4 a = *(const float4*)(ybuf + (size_t)pos0[t] * DD + d);
  const float4 b = *(const float4*)(ybuf + (size_t)pos1[t] * DD + d);
  float4 o; o.x = a.x + b.x; o.y = a.y + b.y; o.z = a.z + b.z; o.w = a.w + b.w;
  *(float4*)(out + (size_t)t * DD + d) = o;
}

extern "C" void kernel_launch(void* const* d_in, const int* in_sizes, int n_in,
                              void* d_out, int out_size, void* d_ws,
                              size_t ws_size, hipStream_t stream) {
  const float* x  = (const float*)d_in[0];
  const float* Wg = (const float*)d_in[1];
  const float* bg = (const float*)d_in[2];
  const float* W1 = (const float*)d_in[3];
  const float* b1 = (const float*)d_in[4];
  const float* W2 = (const float*)d_in[5];
  const float* b2 = (const float*)d_in[6];
  float* out = (float*)d_out;
  char* ws = (char*)d_ws;

  // ---- Tier A: sparse pair-grouped path. Needs ~218.4 MB workspace. ----
  const size_t XB_SZ   = (size_t)NT * DD * 2;          //   8 MiB
  const size_t WT_SZ   = (size_t)NEXP * DD * HH * 2;   //  64 MiB each
  const size_t HB_ROWS = 9216;                         // 8192 pairs + pad
  const size_t HB_SZ   = HB_ROWS * HH * 2;             //  72 MiB
  const size_t W1T_OFF = XB_SZ;
  const size_t W2T_OFF = W1T_OFF + WT_SZ;
  const size_t HB_OFF  = W2T_OFF + WT_SZ;
  const size_t SM_OFF  = HB_OFF + HB_SZ;
  const size_t TIER_A_NEED = SM_OFF + 275456;

  if (ws_size >= TIER_A_NEED) {
    ushort* xb   = (ushort*)ws;
    ushort* w1t  = (ushort*)(ws + W1T_OFF);
    ushort* w2t  = (ushort*)(ws + W2T_OFF);
    ushort* hbuf = (ushort*)(ws + HB_OFF);
    // ybuf overlays w1t (dead after GEMM1): 9216*1024*4 = 37.75 MiB <= 64 MiB
    float*  ybuf = (float*)(ws + W1T_OFF);
    char* sm = ws + SM_OFF;
    int*   counts = (int*)(sm + 0);
    int*   cursor = (int*)(sm + 128);
    int*   base   = (int*)(sm + 256);
    int*   tidx   = (int*)(sm + 1024);
    float* tval   = (float*)(sm + 1024 + 32768);
    int*   perm   = (int*)(sm + 68608);
    float* pairw  = (float*)(sm + 105472);
    float* wgt    = (float*)(sm + 143360);   // dense table (gating scratch)
    int*   pos0   = (int*)(sm + 180224);
    int*   pos1   = (int*)(sm + 196608);

    hipMemsetAsync(sm, 0, 142336, stream);  // counts/cursor/base/perm/pairw

    gating_kernel<<<NT / 4, 256, 0, stream>>>(x, Wg, bg, wgt, tidx, tval, counts);
    cvt_x_kernel<<<(NT * DD / 4 + 255) / 256, 256, 0, stream>>>(x, xb, NT * DD);
    scan_kernel<<<1, 1, 0, stream>>>(counts, base);
    scatter_kernel<<<NT / 256, 256, 0, stream>>>(tidx, tval, base, cursor,
                                                 perm, pairw, pos0, pos1);

    // all-expert weight transposes (fp32 -> bf16, [R][C] -> [C][R])
    transpose_cvt64_kernel<<<dim3(HH / 64, DD / 64, NEXP), 256, 0, stream>>>(W1, w1t, DD, HH);
    transpose_cvt64_kernel<<<dim3(DD / 64, HH / 64, NEXP), 256, 0, stream>>>(W2, w2t, HH, DD);

    // h[p] = relu(x[perm[p]] @ W1_e + b1_e)   (merged over experts)
    gemm_bt_kernel<1, true><<<dim3(HH / 128, NT / 128, NEXP), 256, 0, stream>>>(
        xb, w1t, b1, hbuf, perm, pairw, nullptr, base, counts, HH, DD, 0);
    // ybuf[p] = pairw[p] * (h[p] @ W2_e + b2_e)   (plain stores)
    gemm_bt_kernel<2, true><<<dim3(DD / 128, NT / 128, NEXP), 256, 0, stream>>>(
        hbuf, w2t, b2, ybuf, nullptr, pairw, nullptr, base, counts, DD, HH, 0);
    // out[t] = ybuf[pos0[t]] + ybuf[pos1[t]]
    combine_kernel<<<NT, 256, 0, stream>>>(ybuf, pos0, pos1, out);
    return;
  }

  // ---- Tier B: dense per-expert path (round-1 footprint) ----
  ushort* xb  = (ushort*)ws;                         // 8 MiB
  ushort* hb  = (ushort*)(ws + (8u << 20));          // 32 MiB
  ushort* w1t = (ushort*)(ws + (42u << 20));         // 8 MiB
  ushort* w2t = (ushort*)(ws + (51u << 20));         // 8 MiB
  char* sm2 = ws + (59u << 20);
  int*   tidx   = (int*)(sm2);
  float* tval   = (float*)(sm2 + 32768);
  int*   counts = (int*)(sm2 + 65536);
  int*   pos0   = (int*)(sm2 + 131072);
  int*   pos1   = (int*)(sm2 + 163840);
  float* wgt    = (float*)(ws + (60u << 20));        // 128 KiB

  hipMemsetAsync(d_out, 0, (size_t)out_size * sizeof(float), stream);
  gating_kernel<<<NT / 4, 256, 0, stream>>>(x, Wg, bg, wgt, tidx, tval, counts);
  cvt_x_kernel<<<(NT * DD / 4 + 255) / 256, 256, 0, stream>>>(x, xb, NT * DD);

  for (int e = 0; e < NEXP; e++) {
    transpose_cvt64_kernel<<<dim3(HH / 64, DD / 64, 1), 256, 0, stream>>>(
        W1 + (size_t)e * DD * HH, w1t, DD, HH);
    gemm_bt_kernel<1, false><<<dim3(HH / 128, NT / 128, 1), 256, 0, stream>>>(
        xb, w1t, b1, hb, nullptr, nullptr, nullptr, nullptr, nullptr, HH, DD, e);
    transpose_cvt64_kernel<<<dim3(DD / 64, HH / 64, 1), 256, 0, stream>>>(
        W2 + (size_t)e * HH * DD, w2t, HH, DD);
    gemm_bt_kernel<2, false><<<dim3(DD / 128, NT / 128, 1), 256, 0, stream>>>(
        hb, w2t, b2, out, nullptr, nullptr, wgt, nullptr, nullptr, DD, HH, e);
  }
}